// Round 1
// baseline (27782.401 us; speedup 1.0000x reference)
//
#include <hip/hip_runtime.h>
#include <hip/hip_bf16.h>
#include <cstdint>
#include <cstddef>

// SimpleXLSTM: 2-layer LSTM (B=128, T=512, IN=512, H=1024) + sigmoid head.
// Round 1: multi-kernel graph (1024 step kernels). Fused GEMM(MFMA bf16)+gates
// per (step,layer). Weights pre-transposed to [4096][K] bf16 with gate
// interleave (unit u -> rows 4u+{f,i,o,g}) so each WG's 32-col slice has full
// gates for 8 hidden units.

#define BATCH 128
#define SEQ   512
#define INP   512
#define HID   1024
#define NCOL  4096   // 4*HID

typedef __bf16 bf16x8 __attribute__((ext_vector_type(8)));
typedef float  f32x4  __attribute__((ext_vector_type(4)));
typedef unsigned int u32x4 __attribute__((ext_vector_type(4)));

__device__ __forceinline__ bf16x8 load_bf16x8(const __hip_bfloat16* p) {
    u32x4 u = *reinterpret_cast<const u32x4*>(p);
    return __builtin_bit_cast(bf16x8, u);
}

__device__ __forceinline__ f32x4 mfma16(bf16x8 a, bf16x8 b, f32x4 c) {
    return __builtin_amdgcn_mfma_f32_16x16x32_bf16(a, b, c, 0, 0, 0);
}

__device__ __forceinline__ float sigmoidf_(float x) {
    return 1.0f / (1.0f + expf(-x));
}

// ---------------------------------------------------------------------------
// Prep: W [K][4096] fp32 -> WT [4096][K] bf16 with gate-interleaved rows.
// new row r = (c & 1023)*4 + (c >> 10)   (c = old column, gate-major)
// ---------------------------------------------------------------------------
__global__ __launch_bounds__(1024)
void transpose_reorder_kernel(const float* __restrict__ W,
                              __hip_bfloat16* __restrict__ WT, int K)
{
    __shared__ float tile[32][33];
    const int k0 = blockIdx.x * 32;
    const int c0 = blockIdx.y * 32;
    const int tx = threadIdx.x, ty = threadIdx.y;
    tile[ty][tx] = W[(size_t)(k0 + ty) * NCOL + (c0 + tx)];
    __syncthreads();
    const int c = c0 + ty;
    const int r = (c & 1023) * 4 + (c >> 10);
    WT[(size_t)r * K + (k0 + tx)] = __float2bfloat16(tile[tx][ty]);
}

__global__ void bias_reorder_kernel(const float* __restrict__ b0,
                                    const float* __restrict__ b1,
                                    float* __restrict__ b0r,
                                    float* __restrict__ b1r)
{
    int i = blockIdx.x * blockDim.x + threadIdx.x;  // 0..8191
    if (i >= 2 * NCOL) return;
    const float* src = (i < NCOL) ? b0 : b1;
    float*       dst = (i < NCOL) ? b0r : b1r;
    int c = i & (NCOL - 1);
    dst[(c & 1023) * 4 + (c >> 10)] = src[c];
}

// ---------------------------------------------------------------------------
// One LSTM cell step for one layer: z = [src0, src1] @ W + b, gates, c/h.
// Grid: 256 blocks = 2 M-groups x 128 N-groups (mg in high bit so both
// M-groups of an N-group land on the same XCD -> weight slice stays in L2).
// Block: 256 threads = 4 waves; wave covers 32 rows x 16 cols (2 MFMA accs).
// ---------------------------------------------------------------------------
template<bool X_F32>
__global__ __launch_bounds__(256)
void lstm_step_kernel(const void* __restrict__ src0, long rs0, int KX,
                      const __hip_bfloat16* __restrict__ src1,  // h_prev [B][HID]
                      const __hip_bfloat16* __restrict__ WT,    // [NCOL][Ktot]
                      int Ktot,
                      const float* __restrict__ biasR,          // [NCOL]
                      float* __restrict__ cst,                  // [B][HID] fp32
                      __hip_bfloat16* __restrict__ hout)        // [B][HID]
{
    const int tid  = threadIdx.x;
    const int lane = tid & 63;
    const int w    = tid >> 6;
    const int mg   = blockIdx.x >> 7;    // 0..1  (64 batch rows each)
    const int ng   = blockIdx.x & 127;   // 0..127 (32 interleaved cols each)

    const int mrow0 = mg * 64 + (w & 1) * 32;                   // wave row base
    const int ncol  = ng * 32 + ((w >> 1) & 1) * 16 + (lane & 15);
    const int klane = (lane >> 4) * 8;

    f32x4 acc0 = {0.f, 0.f, 0.f, 0.f};
    f32x4 acc1 = {0.f, 0.f, 0.f, 0.f};

    const __hip_bfloat16* wrow = WT + (size_t)ncol * (size_t)Ktot;
    const int r0 = mrow0 + (lane & 15);
    const int r1 = r0 + 16;

    // ---- part 1: k in [0, KX) from src0 ----
    if (X_F32) {
        const float* a0 = (const float*)src0 + (size_t)r0 * rs0;
        const float* a1 = (const float*)src0 + (size_t)r1 * rs0;
        #pragma unroll 2
        for (int k0 = 0; k0 < KX; k0 += 32) {
            const int k = k0 + klane;
            bf16x8 bfrag = load_bf16x8(wrow + k);
            bf16x8 af0, af1;
            #pragma unroll
            for (int j = 0; j < 8; ++j) {
                af0[j] = (__bf16)a0[k + j];
                af1[j] = (__bf16)a1[k + j];
            }
            acc0 = mfma16(af0, bfrag, acc0);
            acc1 = mfma16(af1, bfrag, acc1);
        }
    } else {
        const __hip_bfloat16* a0 = (const __hip_bfloat16*)src0 + (size_t)r0 * rs0;
        const __hip_bfloat16* a1 = (const __hip_bfloat16*)src0 + (size_t)r1 * rs0;
        #pragma unroll 2
        for (int k0 = 0; k0 < KX; k0 += 32) {
            const int k = k0 + klane;
            bf16x8 bfrag = load_bf16x8(wrow + k);
            acc0 = mfma16(load_bf16x8(a0 + k), bfrag, acc0);
            acc1 = mfma16(load_bf16x8(a1 + k), bfrag, acc1);
        }
    }

    // ---- part 2: k in [KX, Ktot) from src1 (h_prev, stride HID) ----
    {
        const __hip_bfloat16* a0 = src1 + (size_t)r0 * HID;
        const __hip_bfloat16* a1 = src1 + (size_t)r1 * HID;
        const __hip_bfloat16* wk = wrow + KX;
        #pragma unroll 2
        for (int k0 = 0; k0 < HID; k0 += 32) {
            const int k = k0 + klane;
            bf16x8 bfrag = load_bf16x8(wk + k);
            acc0 = mfma16(load_bf16x8(a0 + k), bfrag, acc0);
            acc1 = mfma16(load_bf16x8(a1 + k), bfrag, acc1);
        }
    }

    // ---- epilogue: dump z to LDS, gather 4 gates per hidden unit ----
    __shared__ float zbuf[64][33];
    {
        const int clocal = ((w >> 1) & 1) * 16 + (lane & 15);
        const int rbase  = (w & 1) * 32 + ((lane >> 4) << 2);
        #pragma unroll
        for (int r = 0; r < 4; ++r) {
            zbuf[rbase + r][clocal]      = acc0[r];
            zbuf[rbase + 16 + r][clocal] = acc1[r];
        }
    }
    __syncthreads();

    for (int it = tid; it < 512; it += 256) {
        const int bl = it >> 3;          // local batch row 0..63
        const int u  = it & 7;           // local hidden unit 0..7
        const int b  = mg * 64 + bl;
        const int ug = ng * 8 + u;
        const int cb = ng * 32 + 4 * u;
        float f = zbuf[bl][4 * u + 0] + biasR[cb + 0];
        float i = zbuf[bl][4 * u + 1] + biasR[cb + 1];
        float o = zbuf[bl][4 * u + 2] + biasR[cb + 2];
        float g = zbuf[bl][4 * u + 3] + biasR[cb + 3];
        float cold = cst[b * HID + ug];
        float cn = sigmoidf_(f) * cold + sigmoidf_(i) * tanhf(g);
        float hn = sigmoidf_(o) * tanhf(cn);
        cst[b * HID + ug]  = cn;
        hout[b * HID + ug] = __float2bfloat16(hn);
    }
}

// ---------------------------------------------------------------------------
// Head: out[b] = sigmoid(h1_last[b,:] @ Wout + bout)
// ---------------------------------------------------------------------------
__global__ __launch_bounds__(128)
void final_kernel(const __hip_bfloat16* __restrict__ h1last,
                  const float* __restrict__ Wout,
                  const float* __restrict__ bout,
                  float* __restrict__ out)
{
    const int b = threadIdx.x;
    if (b < BATCH) {
        float acc = 0.f;
        for (int u = 0; u < HID; ++u)
            acc += __bfloat162float(h1last[b * HID + u]) * Wout[u];
        acc += bout[0];
        out[b] = 1.f / (1.f + expf(-acc));
    }
}

// ---------------------------------------------------------------------------
extern "C" void kernel_launch(void* const* d_in, const int* in_sizes, int n_in,
                              void* d_out, int out_size, void* d_ws, size_t ws_size,
                              hipStream_t stream)
{
    const float* x    = (const float*)d_in[0];   // [128][512][512]
    const float* W0   = (const float*)d_in[1];   // [1536][4096]
    const float* b0   = (const float*)d_in[2];   // [4096]
    const float* W1   = (const float*)d_in[3];   // [2048][4096]
    const float* b1   = (const float*)d_in[4];   // [4096]
    const float* Wout = (const float*)d_in[5];   // [1024]
    const float* bout = (const float*)d_in[6];   // [1]
    float* out = (float*)d_out;

    char* ws = (char*)d_ws;
    // workspace layout (bytes)
    const size_t OFF_W0T = 0;                         // 4096*1536*2 = 12,582,912
    const size_t OFF_W1T = 12582912;                  // 4096*2048*2 = 16,777,216
    const size_t OFF_B0R = 29360128;                  // 16,384
    const size_t OFF_B1R = 29376512;                  // 16,384
    const size_t OFF_H0  = 29392896;                  // 2*128*1024*2 = 524,288
    const size_t OFF_H1  = 29917184;                  // 524,288
    const size_t OFF_C0  = 30441472;                  // 128*1024*4 = 524,288
    const size_t OFF_C1  = 30965760;                  // 524,288  (end: 31,490,048)

    __hip_bfloat16* W0T = (__hip_bfloat16*)(ws + OFF_W0T);
    __hip_bfloat16* W1T = (__hip_bfloat16*)(ws + OFF_W1T);
    float* b0r = (float*)(ws + OFF_B0R);
    float* b1r = (float*)(ws + OFF_B1R);
    __hip_bfloat16* h0 = (__hip_bfloat16*)(ws + OFF_H0);
    __hip_bfloat16* h1 = (__hip_bfloat16*)(ws + OFF_H1);
    float* c0 = (float*)(ws + OFF_C0);
    float* c1 = (float*)(ws + OFF_C1);

    // zero all recurrent state (h0/h1 both slots, c0, c1)
    hipMemsetAsync(ws + OFF_H0, 0, 2097152, stream);

    // weight/bias prep (part of the graph; ~30 us, amortized)
    dim3 tb(32, 32);
    transpose_reorder_kernel<<<dim3(48, 128), tb, 0, stream>>>(W0, W0T, 1536);
    transpose_reorder_kernel<<<dim3(64, 128), tb, 0, stream>>>(W1, W1T, 2048);
    bias_reorder_kernel<<<32, 256, 0, stream>>>(b0, b1, b0r, b1r);

    const int HS = BATCH * HID;  // elements per h slot
    for (int t = 0; t < SEQ; ++t) {
        const int cur  = t & 1;
        const int prev = (t + 1) & 1;
        // layer 0: A = [x_t (fp32), h0_prev], W0T (Ktot=1536)
        lstm_step_kernel<true><<<256, 256, 0, stream>>>(
            (const void*)(x + (size_t)t * INP), (long)(SEQ * INP), INP,
            h0 + prev * HS, W0T, INP + HID, b0r, c0, h0 + cur * HS);
        // layer 1: A = [h0_cur, h1_prev], W1T (Ktot=2048)
        lstm_step_kernel<false><<<256, 256, 0, stream>>>(
            (const void*)(h0 + cur * HS), (long)HID, HID,
            h1 + prev * HS, W1T, 2 * HID, b1r, c1, h1 + cur * HS);
    }

    // t=511 wrote slot 511&1 = 1
    final_kernel<<<1, 128, 0, stream>>>(h1 + 1 * HS, Wout, bout, out);
}